// Round 6
// baseline (236.463 us; speedup 1.0000x reference)
//
#include <hip/hip_runtime.h>
#include <hip/hip_bf16.h>

// Reduction of the reference (h0 = 0):
//   z  = sigmoid(x @ Wz + bz),  t = tanh(x @ Wh + bh),  h = (1-z)*t
//   out= sigmoid(relu(h @ fc1) @ fc2)       (w_r/b_r, edge_index dead)
//
// R13 theory: SIX structurally different kernels (R0,R4-R8,R12: register
// dbuf, barriered LDS, wave-private DMA x2, 64/128-B runs, 2/3-deep
// buffers) ALL read x at 1.65 TB/s effective (dur ~= 102.4MB/1.65TB/s in
// every case). No per-wave MLP model fits (nominal outstanding bytes
// varied 50x with zero effect). Conclusion: pattern-level service cap for
// "many independent 32-row gathers" -- NOT fixable by issue structure.
// Fix: make the x-read BE the 6.3 TB/s copy pattern, and halve the bytes:
//  K1 repack_A: grid-stride fully-coalesced fp32 reads (1 wave-instr = one
//    contiguous 1-KB row), RNE-convert to bf16 (numerics identical to the
//    old in-loop f2bf), store 51.2 MB in MFMA-A-fragment order
//    [waveTile][kt][lane][8bf16] (16-B scatter writes, L2-merged).
//  K2 rgcn_main: A-frag = ONE coalesced 16-B/lane load per kt straight
//    into the MFMA operand (wave sweeps its 16 KB sequentially). No A-LDS,
//    no in-loop cvt. LDS = 32 KB B-frags only -> 5 blocks/CU, 20 waves/CU
//    (vs 16%-occupancy before), all 782 blocks resident in one round.
// Diagnostic value: K1/K2 profile separately. K1 slow => cap is
// environmental (near-roofline). K1 fast, K2 slow => consumer-structure.
// NOTE: requires ws_size >= 64 KB + 51.25 MB.

#define NF    256
#define TILE  32            // nodes per wave
#define WPB   4             // waves per block
#define MB    (TILE * WPB)  // 128 nodes per block
#define NTHR  256

typedef __attribute__((ext_vector_type(8)))  short  short8;
typedef __attribute__((ext_vector_type(16))) float  floatx16;

__device__ __forceinline__ unsigned f2bf(float f) {
    __hip_bfloat16 h = __float2bfloat16(f);   // RNE
    return (unsigned)*(unsigned short*)&h;
}
__device__ __forceinline__ float fast_sigmoid(float v) {
    return 1.0f / (1.0f + __expf(-v));
}
__device__ __forceinline__ float fast_tanh(float v) {
    return 1.0f - 2.0f / (1.0f + __expf(2.0f * v));
}
__device__ __forceinline__ void dma16(const void* g, void* l) {
    __builtin_amdgcn_global_load_lds(
        (const __attribute__((address_space(1))) unsigned int*)g,
        (__attribute__((address_space(3))) unsigned int*)l,
        16, 0, 0);
}

// ---- prep: fold w[0]+w[1], emit bf16 in 32x32x16 B-fragment order:
// Wf[((kt*2+nt)*64 + lane)*8 + j] = W[kt*16 + (lane>>5)*8 + j][nt*32 + (lane&31)]
__global__ void prep_W(const float* __restrict__ wz,   // (2, 288, 32)
                       const float* __restrict__ wh,   // (2, 288, 32)
                       unsigned short* __restrict__ Wf) // 16*2*64*8 bf16
{
    int idx = blockIdx.x * blockDim.x + threadIdx.x;   // 0 .. 16383
    if (idx >= NF * 64) return;
    int j    = idx & 7;
    int lane = (idx >> 3) & 63;
    int nt   = (idx >> 9) & 1;
    int kt   = idx >> 10;                  // 0..15
    int k = kt * 16 + (lane >> 5) * 8 + j; // 0..255
    int o = nt * 32 + (lane & 31);         // 0..63
    const int PLANE = 288 * 32;
    float v;
    if (o < 32) v = wz[k * 32 + o]        + wz[PLANE + k * 32 + o];
    else        v = wh[k * 32 + (o - 32)] + wh[PLANE + k * 32 + (o - 32)];
    Wf[idx] = (unsigned short)f2bf(v);
}

// ---- K1: copy-style repack x (fp32, row-major) -> Ap (bf16, A-frag order)
// Ap ushort index: (((tile*4+wv)*16 + kt)*512) + (m + 32*h)*8 + e
//   where row = tile*128 + wv*32 + m, k = kt*16 + h*8 + e+j'
// Each thread handles one float4 (4 consecutive k of one row) -> one
// aligned 8-B store. A wave's 64 lanes cover exactly one 1-KB row (perfect
// read coalescing, the 6.3 TB/s pattern).
__global__ void __launch_bounds__(NTHR)
repack_A(const float* __restrict__ x, unsigned short* __restrict__ Ap,
         int n_nodes)
{
    const int total = n_nodes * 64;                    // float4 count
    for (int i = blockIdx.x * blockDim.x + threadIdx.x; i < total;
         i += gridDim.x * blockDim.x) {
        int row = i >> 6;
        int q   = i & 63;                              // float4 within row
        float4 v = ((const float4*)x)[i];
        unsigned lo = f2bf(v.x) | (f2bf(v.y) << 16);
        unsigned hi = f2bf(v.z) | (f2bf(v.w) << 16);
        int k0   = q << 2;                             // 0..252, step 4
        int tile = row >> 7;
        int wv   = (row >> 5) & 3;
        int m    = row & 31;
        int kt   = k0 >> 4;
        int h    = (k0 >> 3) & 1;
        int e    = k0 & 7;                             // 0 or 4
        size_t base = ((size_t)(tile * 4 + wv) * 16 + kt) * 512
                      + (size_t)(m + 32 * h) * 8 + e;
        *(uint2*)(Ap + base) = make_uint2(lo, hi);     // 4 bf16, 8 B aligned
    }
}

// ---- K2: GEMM from pre-packed A + fused gates + fc head.
__global__ void __launch_bounds__(NTHR, 5)
rgcn_main(const unsigned short* __restrict__ Ap,  // A-frags (ws)
          const unsigned short* __restrict__ Wf,  // B-frags (ws, 32 KB)
          const float* __restrict__ bz,    // [32]
          const float* __restrict__ bh,    // [32]
          const float* __restrict__ fc1w,  // [32][32] (in,out)
          const float* __restrict__ fc1b,  // [32]
          const float* __restrict__ fc2w,  // [32]
          const float* __restrict__ fc2b,  // [1]
          float* __restrict__ out,         // [N]
          int n_nodes)
{
    __shared__ __align__(16) char SBf[32 * 1024];      // 32 KB: B frags (+H epi)

    const int tid   = threadIdx.x;
    const int lane  = tid & 63;
    const int wave  = tid >> 6;              // 0..3
    const int node0 = blockIdx.x * MB + wave * TILE;

    // ---- stage B via global_load_lds: wave w -> groups w*8 .. w*8+7.
    {
        const char* wsrc = (const char*)Wf;
#pragma unroll
        for (int i = 0; i < 8; ++i) {
            int g = wave * 8 + i;
            dma16(wsrc + (size_t)g * 1024 + lane * 16, SBf + g * 1024);
        }
    }
    const int nc  = lane & 31;
    const float bzn = bz[nc];
    const float bhn = bh[nc];

    asm volatile("s_waitcnt vmcnt(0)" ::: "memory");
    __syncthreads();                         // B visible to all waves

    // ---- K-loop: per kt, one coalesced 16-B/lane A load (sequential
    // 1-KB wave-instrs over this wave's 16 KB span) + 2 LDS B reads +
    // 2 MFMA. Plain loads: compiler schedules/prefetches.
    const unsigned short* aw =
        Ap + ((size_t)(blockIdx.x * WPB + wave) * 16) * 512 + lane * 8;
    const char* bl = SBf + lane * 16;

    floatx16 acc0 = {};                      // z cols (nt=0)
    floatx16 acc1 = {};                      // h cols (nt=1)

#pragma unroll
    for (int kt = 0; kt < 16; ++kt) {
        short8 a = *(const short8*)(aw + (size_t)kt * 512);
        uint4 b0u = *(const uint4*)(bl + (size_t)(2 * kt    ) * 1024);
        uint4 b1u = *(const uint4*)(bl + (size_t)(2 * kt + 1) * 1024);
        union { short8 s; unsigned u[4]; } B0, B1;
        B0.u[0] = b0u.x; B0.u[1] = b0u.y; B0.u[2] = b0u.z; B0.u[3] = b0u.w;
        B1.u[0] = b1u.x; B1.u[1] = b1u.y; B1.u[2] = b1u.z; B1.u[3] = b1u.w;
        acc0 = __builtin_amdgcn_mfma_f32_32x32x16_bf16(a, B0.s, acc0, 0, 0, 0);
        acc1 = __builtin_amdgcn_mfma_f32_32x32x16_bf16(a, B1.s, acc1, 0, 0, 0);
    }

    // All waves done reading B before we overwrite SBf with H tiles.
    __syncthreads();

    // ---- epilogue: gates in-register (C/D: col=lane&31,
    // row=(reg&3)+8*(reg>>2)+4*(lane>>5)); H tile in this wave's 8-KB SBf
    // slice, XOR-swizzled (slot ^= row&7) so the transpose read is 2-way.
    float* Hw = (float*)(SBf + wave * 8192);
#pragma unroll
    for (int r = 0; r < 16; ++r) {
        int row = (r & 3) + 8 * (r >> 2) + 4 * (lane >> 5);
        float z = fast_sigmoid(acc0[r] + bzn);
        float t = fast_tanh   (acc1[r] + bhn);
        int boff = row * 128 + ((((nc >> 2) ^ (row & 7)) << 4) | ((nc & 3) << 2));
        *(float*)((char*)Hw + boff) = (1.0f - z) * t;
    }
    // within-wave DS ordering: drain writes before cross-lane reads
    asm volatile("s_waitcnt lgkmcnt(0)" ::: "memory");

    const int nl   = lane & 31;
    const int half = lane >> 5;
    float hbuf[32];
#pragma unroll
    for (int q = 0; q < 8; ++q) {
        int boff = nl * 128 + ((q ^ (nl & 7)) << 4);
        float4 v = *(const float4*)((char*)Hw + boff);
        hbuf[q * 4 + 0] = v.x; hbuf[q * 4 + 1] = v.y;
        hbuf[q * 4 + 2] = v.z; hbuf[q * 4 + 3] = v.w;
    }
    float part = 0.0f;
    for (int jj = 0; jj < 16; ++jj) {
        int j = (half << 4) + jj;            // 2 addrs/wave -> broadcastish
        float s = fc1b[j];
#pragma unroll
        for (int o = 0; o < 32; ++o)
            s = fmaf(hbuf[o], fc1w[o * 32 + j], s);
        part = fmaf(fmaxf(s, 0.0f), fc2w[j], part);
    }
    part += __shfl_xor(part, 32);            // combine the two j-halves
    if (half == 0) {
        int gn = node0 + nl;
        if (gn < n_nodes)
            out[gn] = fast_sigmoid(part + fc2b[0]);   // 32-lane coalesced
    }
}

extern "C" void kernel_launch(void* const* d_in, const int* in_sizes, int n_in,
                              void* d_out, int out_size, void* d_ws, size_t ws_size,
                              hipStream_t stream) {
    // 0:x 1:edge_index(dead) 2:w_z 3:b_z 4:w_r(dead) 5:b_r(dead)
    // 6:w_h 7:b_h 8:fc1_w 9:fc1_b 10:fc2_w 11:fc2_b
    const float* x    = (const float*)d_in[0];
    const float* wz   = (const float*)d_in[2];
    const float* bz   = (const float*)d_in[3];
    const float* wh   = (const float*)d_in[6];
    const float* bh   = (const float*)d_in[7];
    const float* fc1w = (const float*)d_in[8];
    const float* fc1b = (const float*)d_in[9];
    const float* fc2w = (const float*)d_in[10];
    const float* fc2b = (const float*)d_in[11];
    float* out = (float*)d_out;

    unsigned short* Wf = (unsigned short*)d_ws;              // 32 KB B-frags
    unsigned short* Ap = (unsigned short*)((char*)d_ws + 65536); // 51.25 MB

    const int n = in_sizes[0] / NF;   // 100000

    prep_W  <<<(NF * 64 + 255) / 256, 256, 0, stream>>>(wz, wh, Wf);
    repack_A<<<2048, NTHR, 0, stream>>>(x, Ap, n);
    rgcn_main<<<(n + MB - 1) / MB, NTHR, 0, stream>>>(
        Ap, Wf, bz, bh, fc1w, fc1b, fc2w, fc2b, out, n);
}

// Round 8
// 204.719 us; speedup vs baseline: 1.1551x; 1.1551x over previous
//
#include <hip/hip_runtime.h>
#include <hip/hip_bf16.h>

// Reduction of the reference (h0 = 0):
//   z  = sigmoid(x @ Wz + bz),  t = tanh(x @ Wh + bh),  h = (1-z)*t
//   out= sigmoid(relu(h @ fc1) @ fc2)       (w_r/b_r, edge_index dead)
// Main cost: [100000,256] @ [256,64] -> bf16 MFMA, memory-bound on x.
//
// R15 (final): revert to the twice-harness-proven R0 register-path kernel.
// Session findings:
//  - R0,R4-R8,R12 (register dbuf / barriered LDS / wave-private DMA with
//    counted vmcnt, 64-128B runs, 2-3-deep buffers) ALL read x at
//    1.53-1.66 TB/s. R13's copy-control (repack_A: 8 VGPR, 54% occ,
//    perfectly-coalesced float4 streams) ALSO hit 1.53 TB/s => a
//    pattern/occupancy/depth-independent service cap ~1.6 TB/s governs
//    this op on this rig (short isolated dispatches; DVFS never ramps).
//    Floor = 102.4 MB fp32 input / 1.6 TB/s ~= 64 us + ~138 us fixed
//    harness overhead => ~202 us total. Every passing variant lands there.
//  - R12's hand-scheduled DMA pipeline passed once (R5) then failed the
//    post-timing divergence tripwire once (R14, absmax 0.31 after many
//    graph replays): a low-probability race in the counted-vmcnt /
//    LDS-alias machinery that a single pass does not screen (m152).
//    Since ALL structures perform identically at the service cap, pick
//    the one with zero inline-asm waits in the K-loop, no LDS aliasing,
//    and two full-harness passes: this one (202.3 us R0; 203.4 us prior
//    session). Perf delta to R12: 0.3% — race risk not worth it.

#define NF    256
#define TILE  32            // nodes per wave
#define WPB   4             // waves per block
#define MB    (TILE * WPB)  // 128 nodes per block
#define NTHR  256
#define BGRP  1040          // bytes per B fragment-group (1024 + 16 pad)
#define HSTR  36            // epilogue Hs row stride (floats)

typedef __attribute__((ext_vector_type(8)))  short  short8;
typedef __attribute__((ext_vector_type(16))) float  floatx16;

__device__ __forceinline__ unsigned f2bf(float f) {
    __hip_bfloat16 h = __float2bfloat16(f);   // RNE
    return (unsigned)*(unsigned short*)&h;
}
__device__ __forceinline__ float fast_sigmoid(float v) {
    return 1.0f / (1.0f + __expf(-v));
}
__device__ __forceinline__ float fast_tanh(float v) {
    return 1.0f - 2.0f / (1.0f + __expf(2.0f * v));
}

// ---- prep: fold w[0]+w[1], emit bf16 in 32x32x16 B-fragment order:
// Wf[((kt*2+nt)*64 + lane)*8 + j] = W[kt*16 + (lane>>5)*8 + j][nt*32 + (lane&31)]
__global__ void prep_W(const float* __restrict__ wz,   // (2, 288, 32)
                       const float* __restrict__ wh,   // (2, 288, 32)
                       unsigned short* __restrict__ Wf) // 16*2*64*8 bf16
{
    int idx = blockIdx.x * blockDim.x + threadIdx.x;   // 0 .. 16383
    if (idx >= NF * 64) return;
    int j    = idx & 7;
    int lane = (idx >> 3) & 63;
    int nt   = (idx >> 9) & 1;
    int kt   = idx >> 10;                  // 0..15
    int k = kt * 16 + (lane >> 5) * 8 + j; // 0..255
    int o = nt * 32 + (lane & 31);         // 0..63
    const int PLANE = 288 * 32;
    float v;
    if (o < 32) v = wz[k * 32 + o]        + wz[PLANE + k * 32 + o];
    else        v = wh[k * 32 + (o - 32)] + wh[PLANE + k * 32 + (o - 32)];
    Wf[idx] = (unsigned short)f2bf(v);
}

__global__ void __launch_bounds__(NTHR, 3)
rgcn_main(const float* __restrict__ x,     // [N, 256]
          const unsigned short* __restrict__ Wf, // B-frags (ws)
          const float* __restrict__ bz,    // [32]
          const float* __restrict__ bh,    // [32]
          const float* __restrict__ fc1w,  // [32][32] (in,out)
          const float* __restrict__ fc1b,  // [32]
          const float* __restrict__ fc2w,  // [32]
          const float* __restrict__ fc2b,  // [1]
          float* __restrict__ out,         // [N]
          int n_nodes)
{
    __shared__ __align__(16) char SB[32 * BGRP];        // 33280 B: B frags
    __shared__ float Hs[WPB * TILE * HSTR];             // 18432 B: epilogue

    const int tid   = threadIdx.x;
    const int lane  = tid & 63;
    const int wave  = tid >> 6;              // 0..3
    const int node0 = blockIdx.x * MB;

    // ---- stage B fragments into LDS once (32 KB, L2-hot source).
    // group g = kt*2+nt at byte g*BGRP; within group: lane*16.
    {
        const uint4* src = (const uint4*)Wf;             // 2048 uint4
#pragma unroll
        for (int i = 0; i < 8; ++i) {
            int q = i * NTHR + tid;                      // coalesced
            uint4 v = src[q];
            *(uint4*)(SB + (q >> 6) * BGRP + (q & 63) * 16) = v;
        }
    }
    __syncthreads();   // the only block-wide barrier

    // ---- A source: lane's own node row (clamped), 8 floats per kt
    const int m  = lane & 31;
    int gn_a = node0 + wave * TILE + m;
    if (gn_a >= n_nodes) gn_a = n_nodes - 1;   // junk but finite
    const float* xr = x + (size_t)gn_a * NF + (lane >> 5) * 8;

    floatx16 acc0 = {};                      // z cols (nt=0)
    floatx16 acc1 = {};                      // h cols (nt=1)

    float4 bufA[8], bufB[8];
    const char* bl = SB + lane * 16;

    // issue chunk 0 (4 kt = 8 float4 per lane)
#pragma unroll
    for (int t = 0; t < 8; ++t)
        bufA[t] = *(const float4*)(xr + (t >> 1) * 16 + (t & 1) * 4);
    __builtin_amdgcn_sched_barrier(0);

#pragma unroll
    for (int c = 0; c < 4; ++c) {
        // prefetch chunk c+1 into the other buffer, pinned above compute
        if (c < 3) {
            float4* nb = ((c & 1) == 0) ? bufB : bufA;
            const float* xc = xr + (c + 1) * 64;
#pragma unroll
            for (int t = 0; t < 8; ++t)
                nb[t] = *(const float4*)(xc + (t >> 1) * 16 + (t & 1) * 4);
            __builtin_amdgcn_sched_barrier(0);
        }
        // compute chunk c from the current buffer
        const float4* cb = ((c & 1) == 0) ? bufA : bufB;
#pragma unroll
        for (int kt = 0; kt < 4; ++kt) {
            float4 v0 = cb[kt * 2];
            float4 v1 = cb[kt * 2 + 1];
            int g = (c * 4 + kt) * 2;
            uint4 b0u = *(const uint4*)(bl + (size_t)g * BGRP);
            uint4 b1u = *(const uint4*)(bl + (size_t)(g + 1) * BGRP);
            union { short8 s; unsigned u[4]; } a, b0, b1;
            a.u[0] = f2bf(v0.x) | (f2bf(v0.y) << 16);
            a.u[1] = f2bf(v0.z) | (f2bf(v0.w) << 16);
            a.u[2] = f2bf(v1.x) | (f2bf(v1.y) << 16);
            a.u[3] = f2bf(v1.z) | (f2bf(v1.w) << 16);
            b0.u[0] = b0u.x; b0.u[1] = b0u.y; b0.u[2] = b0u.z; b0.u[3] = b0u.w;
            b1.u[0] = b1u.x; b1.u[1] = b1u.y; b1.u[2] = b1u.z; b1.u[3] = b1u.w;
            acc0 = __builtin_amdgcn_mfma_f32_32x32x16_bf16(a.s, b0.s, acc0, 0, 0, 0);
            acc1 = __builtin_amdgcn_mfma_f32_32x32x16_bf16(a.s, b1.s, acc1, 0, 0, 0);
        }
    }

    // ---- epilogue (wave-private): gates in-register (C/D: col=lane&31,
    // row=(reg&3)+8*(reg>>2)+4*(lane>>5)), h -> LDS, split fc head.
    float* Hw = Hs + wave * TILE * HSTR;
    const int nc = lane & 31;
    const float bzn = bz[nc];
    const float bhn = bh[nc];
#pragma unroll
    for (int r = 0; r < 16; ++r) {
        int row = (r & 3) + 8 * (r >> 2) + 4 * (lane >> 5);
        float z = fast_sigmoid(acc0[r] + bzn);
        float t = fast_tanh   (acc1[r] + bhn);
        Hw[row * HSTR + nc] = (1.0f - z) * t;
    }
    // within-wave DS ordering: drain writes before cross-lane reads
    asm volatile("s_waitcnt lgkmcnt(0)" ::: "memory");

    const int nl   = lane & 31;
    const int half = lane >> 5;
    const float* hp = Hw + nl * HSTR;
    float h[32];
#pragma unroll
    for (int q = 0; q < 8; ++q) {
        float4 v = *(const float4*)(hp + q * 4);
        h[q * 4 + 0] = v.x; h[q * 4 + 1] = v.y;
        h[q * 4 + 2] = v.z; h[q * 4 + 3] = v.w;
    }
    float part = 0.0f;
    for (int jj = 0; jj < 16; ++jj) {
        int j = (half << 4) + jj;            // 2 addrs/wave -> broadcastish
        float s = fc1b[j];
#pragma unroll
        for (int o = 0; o < 32; ++o)
            s = fmaf(h[o], fc1w[o * 32 + j], s);
        part = fmaf(fmaxf(s, 0.0f), fc2w[j], part);
    }
    part += __shfl_xor(part, 32);            // combine the two j-halves
    if (half == 0) {
        int gn = node0 + wave * TILE + nl;
        if (gn < n_nodes)
            out[gn] = fast_sigmoid(part + fc2b[0]);   // 32-lane coalesced
    }
}

extern "C" void kernel_launch(void* const* d_in, const int* in_sizes, int n_in,
                              void* d_out, int out_size, void* d_ws, size_t ws_size,
                              hipStream_t stream) {
    // 0:x 1:edge_index(dead) 2:w_z 3:b_z 4:w_r(dead) 5:b_r(dead)
    // 6:w_h 7:b_h 8:fc1_w 9:fc1_b 10:fc2_w 11:fc2_b
    const float* x    = (const float*)d_in[0];
    const float* wz   = (const float*)d_in[2];
    const float* bz   = (const float*)d_in[3];
    const float* wh   = (const float*)d_in[6];
    const float* bh   = (const float*)d_in[7];
    const float* fc1w = (const float*)d_in[8];
    const float* fc1b = (const float*)d_in[9];
    const float* fc2w = (const float*)d_in[10];
    const float* fc2b = (const float*)d_in[11];
    float* out = (float*)d_out;
    unsigned short* Wf = (unsigned short*)d_ws;   // 32 KB of B-fragments

    const int n = in_sizes[0] / NF;   // 100000

    prep_W<<<(NF * 64 + 255) / 256, 256, 0, stream>>>(wz, wh, Wf);
    rgcn_main<<<(n + MB - 1) / MB, NTHR, 0, stream>>>(
        x, Wf, bz, bh, fc1w, fc1b, fc2w, fc2b, out, n);
}